// Round 1
// 187.069 us; speedup vs baseline: 1.0739x; 1.0739x over previous
//
#include <hip/hip_runtime.h>

#define B 4
#define C 256
#define CQ 32
#define NN 13824   // 24^3
#define MM 1728    // 12^3
#define MS 12

typedef __attribute__((ext_vector_type(8))) short short8;    // 8 bf16 = 4 VGPRs
typedef __attribute__((ext_vector_type(4))) float float4_;   // 16x16 MFMA C/D
typedef __attribute__((ext_vector_type(16))) float floatx16; // 32x32 MFMA C/D

static __device__ inline unsigned rne_bf16(float x) {
  unsigned u = __float_as_uint(x);
  u += 0x7FFFu + ((u >> 16) & 1u);   // round-to-nearest-even bf16
  return u >> 16;
}

// ---------------------------------------------------------------------------
// K0: pack Wf/Wg/Wh (fp32 [32][256] each) -> bf16 W16c[ch][kq][m][kk]
//     (ch=K/32 chunk, kq=8-elem k-group, m=0..95 stacked f|g|h, kk=0..7).
//     This is exactly the 16B A-fragment order proj_mfma stages from.
// ---------------------------------------------------------------------------
__global__ __launch_bounds__(256) void wcvt_kernel(
    const float* __restrict__ Wf, const float* __restrict__ Wg,
    const float* __restrict__ Wh, unsigned short* __restrict__ W16c) {
  const int i = blockIdx.x * 256 + threadIdx.x;   // [0, 24576)
  const int kk = i & 7;
  const int rest = i >> 3;
  const int m = rest % 96;
  const int r = rest / 96;
  const int kq = r & 3;
  const int ch = r >> 2;
  const int k = ch * 32 + kq * 8 + kk;
  const float* Wr = (m < 32) ? (Wf + m * C) : (m < 64) ? (Wg + (m - 32) * C)
                                                       : (Wh + (m - 64) * C);
  W16c[i] = (unsigned short)rne_bf16(Wr[k]);
}

// ---------------------------------------------------------------------------
// K1: projections as MFMA GEMM.  [96,256] x [256, NN] per batch.
// (unchanged from r6)
// ---------------------------------------------------------------------------
__global__ __launch_bounds__(256) void proj_mfma(
    const float* __restrict__ x, const unsigned short* __restrict__ W16c,
    unsigned short* __restrict__ f16, unsigned short* __restrict__ g16,
    unsigned short* __restrict__ h16) {
  __shared__ __align__(16) unsigned short xls[2][4][128][8];  // 16 KB
  __shared__ __align__(16) unsigned short wls[2][4][96][8];   // 12 KB
  const int blk = blockIdx.x;
  const int b = blk / 108;
  const int n0 = (blk - b * 108) * 128;
  const int t = threadIdx.x;
  const int w = t >> 6, lane = t & 63;
  const int col = lane & 31, hi = lane >> 5;
  const int sn = t & 127, sh = t >> 7;            // staging: n, k-half

  floatx16 accf = {0}, accg = {0}, acch = {0};

  // ---- stage chunk 0
  {
    const float* xp = x + ((size_t)b * C) * NN + n0 + sn;
#pragma unroll
    for (int it = 0; it < 2; ++it) {
      const int kq = sh * 2 + it;
      float v[8];
#pragma unroll
      for (int kk = 0; kk < 8; ++kk) v[kk] = xp[(size_t)(kq * 8 + kk) * NN];
      *reinterpret_cast<uint4*>(&xls[0][kq][sn][0]) =
          make_uint4(rne_bf16(v[0]) | (rne_bf16(v[1]) << 16),
                     rne_bf16(v[2]) | (rne_bf16(v[3]) << 16),
                     rne_bf16(v[4]) | (rne_bf16(v[5]) << 16),
                     rne_bf16(v[6]) | (rne_bf16(v[7]) << 16));
    }
    const uint4* src = reinterpret_cast<const uint4*>(W16c);
    uint4* dst = reinterpret_cast<uint4*>(&wls[0][0][0][0]);
    dst[t] = src[t];
    if (t < 128) dst[256 + t] = src[256 + t];
  }
  __syncthreads();

  for (int ch = 0; ch < 8; ++ch) {
    const int buf = ch & 1;
    if (ch < 7) {    // stage next chunk into other buffer
      const float* xp = x + ((size_t)b * C + (ch + 1) * 32) * NN + n0 + sn;
#pragma unroll
      for (int it = 0; it < 2; ++it) {
        const int kq = sh * 2 + it;
        float v[8];
#pragma unroll
        for (int kk = 0; kk < 8; ++kk) v[kk] = xp[(size_t)(kq * 8 + kk) * NN];
        *reinterpret_cast<uint4*>(&xls[buf ^ 1][kq][sn][0]) =
            make_uint4(rne_bf16(v[0]) | (rne_bf16(v[1]) << 16),
                       rne_bf16(v[2]) | (rne_bf16(v[3]) << 16),
                       rne_bf16(v[4]) | (rne_bf16(v[5]) << 16),
                       rne_bf16(v[6]) | (rne_bf16(v[7]) << 16));
      }
      const uint4* src =
          reinterpret_cast<const uint4*>(W16c + (size_t)(ch + 1) * 3072);
      uint4* dst = reinterpret_cast<uint4*>(&wls[buf ^ 1][0][0][0]);
      dst[t] = src[t];
      if (t < 128) dst[256 + t] = src[256 + t];
    }
#pragma unroll
    for (int ks = 0; ks < 2; ++ks) {
      const int kq = ks * 2 + hi;
      const short8 bfr = *reinterpret_cast<const short8*>(&xls[buf][kq][w * 32 + col][0]);
      const short8 a0 = *reinterpret_cast<const short8*>(&wls[buf][kq][col][0]);
      const short8 a1 = *reinterpret_cast<const short8*>(&wls[buf][kq][32 + col][0]);
      const short8 a2 = *reinterpret_cast<const short8*>(&wls[buf][kq][64 + col][0]);
      accf = __builtin_amdgcn_mfma_f32_32x32x16_bf16(a0, bfr, accf, 0, 0, 0);
      accg = __builtin_amdgcn_mfma_f32_32x32x16_bf16(a1, bfr, accg, 0, 0, 0);
      acch = __builtin_amdgcn_mfma_f32_32x32x16_bf16(a2, bfr, acch, 0, 0, 0);
    }
    __syncthreads();
  }

  // ---- epilogue. D layout: col=lane&31 (x n-index), row=(r&3)+8*(r>>2)+4*hi.
  const int n = n0 + w * 32 + col;
  {  // f: bf16 [b][n][c], pack row-pairs -> 8 dword stores
    unsigned short* fp = f16 + ((size_t)b * NN + n) * 32 + hi * 4;
#pragma unroll
    for (int rp = 0; rp < 8; ++rp) {
      const int m = (rp & 1) * 2 + 8 * (rp >> 1);   // 0,2,8,10,16,18,24,26
      *reinterpret_cast<unsigned*>(fp + m) =
          rne_bf16(accf[rp * 2]) | (rne_bf16(accf[rp * 2 + 1]) << 16);
    }
  }
  unsigned short* gp = g16 + (size_t)b * CQ * NN + n;
  unsigned short* hp = h16 + (size_t)b * CQ * NN + n;
#pragma unroll
  for (int r = 0; r < 16; ++r) {
    const int c = (r & 3) + 8 * (r >> 2) + 4 * hi;
    gp[(size_t)c * NN] = (unsigned short)rne_bf16(accg[r]);
    hp[(size_t)c * NN] = (unsigned short)rne_bf16(acch[r]);
  }
}

// ---------------------------------------------------------------------------
// K2: 2x2x2 maxpool, bf16 in -> bf16 out. (unchanged from r6)
// ---------------------------------------------------------------------------
__global__ __launch_bounds__(256) void pool_kernel(
    const unsigned short* __restrict__ g16, const unsigned short* __restrict__ h16,
    unsigned short* __restrict__ gt16, unsigned short* __restrict__ ht16) {
  int i = blockIdx.x * 256 + threadIdx.x;            // [0, B*CQ*MM)
  const int c = i & 31;
  const int rest = i >> 5;
  const int m = rest % MM;
  const int b = rest / MM;
  const int wq = m % MS;
  const int hq = (m / MS) % MS;
  const int dq = m / (MS * MS);
  const size_t base = ((size_t)b * CQ + c) * NN +
                      (2 * dq) * 576 + (2 * hq) * 24 + (2 * wq);
  auto mx2 = [](unsigned u) {
    return fmaxf(__uint_as_float(u << 16), __uint_as_float(u & 0xFFFF0000u));
  };
  const unsigned short* pg = g16 + base;
  const unsigned short* ph = h16 + base;
  float vg = fmaxf(fmaxf(mx2(*(const unsigned*)(pg)),
                         mx2(*(const unsigned*)(pg + 24))),
                   fmaxf(mx2(*(const unsigned*)(pg + 576)),
                         mx2(*(const unsigned*)(pg + 600))));
  float vh = fmaxf(fmaxf(mx2(*(const unsigned*)(ph)),
                         mx2(*(const unsigned*)(ph + 24))),
                   fmaxf(mx2(*(const unsigned*)(ph + 576)),
                         mx2(*(const unsigned*)(ph + 600))));
  gt16[((size_t)b * MM + m) * 32 + c] = (unsigned short)(__float_as_uint(vg) >> 16);
  ht16[((size_t)b * 32 + c) * MM + m] = (unsigned short)(__float_as_uint(vh) >> 16);
}

// ---------------------------------------------------------------------------
// K3: MFMA flash attention + FUSED output projection/residual.
// Main loop unchanged from r6. Epilogue: o (fp32, in regs) -> padded LDS
// [64][33] (bank-rotated, conflict-free 64-lane reads), then each wave
// computes 64 output channels for its block's 64 n-columns:
//   out[b][c][n] = gamma * (Wv[c,:] . o[n,:]) + x[b][c][n]
// Wv rows are wave-uniform (readfirstlane on t>>6) -> s_load scalar path.
// x loads pipelined 8-deep to cover HBM latency (the standalone out_kernel
// was latency-bound at 30% BW).
// ---------------------------------------------------------------------------
__global__ __launch_bounds__(256, 4) void attn_kernel(
    const unsigned short* __restrict__ f16, const unsigned short* __restrict__ gt,
    const unsigned short* __restrict__ ht, const float* __restrict__ x,
    const float* __restrict__ Wv, const float* __restrict__ gamma,
    float* __restrict__ out) {
  __shared__ __align__(16) unsigned short sm[16896];
  const int blk = blockIdx.x;               // 864
  const int b = blk / 216;
  const int n0 = (blk - b * 216) * 64;
  const int t = threadIdx.x;
  const int w = t >> 6, L = t & 63, Q = L >> 4, col = L & 15;

  unsigned short* fls = sm;
  unsigned short* g0 = sm + 2560;
  unsigned short* g1 = sm + 5120;
  unsigned short* h0 = sm + 7680;
  unsigned short* h1 = sm + 9984;
  unsigned short* Pls = sm + 12288 + w * 1152;

  {
    const unsigned short* fsrc = f16 + ((size_t)(b * NN + n0)) * 32;
    *reinterpret_cast<uint4*>(fls + (t >> 2) * 40 + (t & 3) * 8) =
        *reinterpret_cast<const uint4*>(fsrc + t * 8);
  }
  const unsigned short* gsrc = gt + (size_t)b * MM * 32;
  const unsigned short* hsrc = ht + (size_t)b * 32 * MM;
  const int gk = t >> 2, gseg = t & 3;
  const int hc = t >> 3, hseg = t & 7;
  *reinterpret_cast<uint4*>(g0 + gk * 40 + gseg * 8) =
      *reinterpret_cast<const uint4*>(gsrc + gk * 32 + gseg * 8);
  *reinterpret_cast<uint4*>(h0 + hc * 72 + hseg * 8) =
      *reinterpret_cast<const uint4*>(hsrc + (size_t)hc * MM + hseg * 8);
  __syncthreads();

  const short8 fB = *reinterpret_cast<const short8*>(fls + (w * 16 + col) * 40 + Q * 8);

  float4_ acc0 = {0.f, 0.f, 0.f, 0.f}, acc1 = {0.f, 0.f, 0.f, 0.f};
  float l = 0.f;

  for (int ch = 0; ch < 27; ++ch) {
    unsigned short* gcur = (ch & 1) ? g1 : g0;
    unsigned short* hcur = (ch & 1) ? h1 : h0;
    uint4 gnx, hnx;
    if (ch < 26) {
      const int k0 = (ch + 1) * 64;
      gnx = *reinterpret_cast<const uint4*>(gsrc + (size_t)(k0 + gk) * 32 + gseg * 8);
      hnx = *reinterpret_cast<const uint4*>(hsrc + (size_t)hc * MM + k0 + hseg * 8);
    }
    float4_ sc[4];
#pragma unroll
    for (int T = 0; T < 4; ++T) {
      const short8 gA =
          *reinterpret_cast<const short8*>(gcur + (T * 16 + col) * 40 + Q * 8);
      float4_ z = {0.f, 0.f, 0.f, 0.f};
      sc[T] = __builtin_amdgcn_mfma_f32_16x16x32_bf16(gA, fB, z, 0, 0, 0);
    }
#pragma unroll
    for (int T = 0; T < 4; ++T) {
      const float p0 = __expf(sc[T][0] - 30.f);
      const float p1 = __expf(sc[T][1] - 30.f);
      const float p2 = __expf(sc[T][2] - 30.f);
      const float p3 = __expf(sc[T][3] - 30.f);
      l += (p0 + p1) + (p2 + p3);
      unsigned short* pw = Pls + col * 72 + T * 16 + Q * 4;
      *reinterpret_cast<uint2*>(pw) =
          make_uint2(rne_bf16(p0) | (rne_bf16(p1) << 16),
                     rne_bf16(p2) | (rne_bf16(p3) << 16));
    }
#pragma unroll
    for (int ks = 0; ks < 2; ++ks) {
      const short8 pA =
          *reinterpret_cast<const short8*>(Pls + col * 72 + ks * 32 + Q * 8);
      const short8 hB0 =
          *reinterpret_cast<const short8*>(hcur + col * 72 + ks * 32 + Q * 8);
      const short8 hB1 =
          *reinterpret_cast<const short8*>(hcur + (16 + col) * 72 + ks * 32 + Q * 8);
      acc0 = __builtin_amdgcn_mfma_f32_16x16x32_bf16(pA, hB0, acc0, 0, 0, 0);
      acc1 = __builtin_amdgcn_mfma_f32_16x16x32_bf16(pA, hB1, acc1, 0, 0, 0);
    }
    if (ch < 26) {
      unsigned short* gnb = (ch & 1) ? g0 : g1;
      unsigned short* hnb = (ch & 1) ? h0 : h1;
      *reinterpret_cast<uint4*>(gnb + gk * 40 + gseg * 8) = gnx;
      *reinterpret_cast<uint4*>(hnb + hc * 72 + hseg * 8) = hnx;
    }
    __syncthreads();
  }

  // ---- softmax denominator + park o in LDS (padded stride 33: bank =
  //      (nl+q)%32 for the epilogue's [lane][q] read -> conflict-free).
  l += __shfl_xor(l, 16);
  l += __shfl_xor(l, 32);
  float* ols = reinterpret_cast<float*>(sm);   // [64][33] fp32 = 8448 B
#pragma unroll
  for (int r = 0; r < 4; ++r) {
    const float linv = 1.f / __shfl(l, Q * 4 + r);
    const int nl = w * 16 + Q * 4 + r;
    ols[nl * 33 + col] = acc0[r] * linv;
    ols[nl * 33 + 16 + col] = acc1[r] * linv;
  }
  __syncthreads();

  // ---- fused out-projection: wave cg handles channels [cg*64, cg*64+64),
  //      lane handles n = n0 + (t&63). x/out accesses are 256B-coalesced.
  const int nl = t & 63;
  const int cg = __builtin_amdgcn_readfirstlane(t >> 6);  // wave-uniform -> s_load Wv
  float ov[CQ];
#pragma unroll
  for (int q = 0; q < CQ; ++q) ov[q] = ols[nl * 33 + q];
  const float gm = gamma[0];
  const float* xb = x + ((size_t)b * C + cg * 64) * NN + n0 + nl;
  float* ob = out + ((size_t)b * C + cg * 64) * NN + n0 + nl;
  float xv[8];
#pragma unroll
  for (int j = 0; j < 8; ++j) xv[j] = xb[(size_t)j * NN];
#pragma unroll
  for (int cc = 0; cc < 64; cc += 8) {
    float xn[8];
    if (cc < 56) {
#pragma unroll
      for (int j = 0; j < 8; ++j) xn[j] = xb[(size_t)(cc + 8 + j) * NN];
    }
#pragma unroll
    for (int j = 0; j < 8; ++j) {
      const float* wr = Wv + (cg * 64 + cc + j) * CQ;
      float s = 0.f;
#pragma unroll
      for (int q = 0; q < CQ; ++q) s = fmaf(wr[q], ov[q], s);
      ob[(size_t)(cc + j) * NN] = gm * s + xv[j];
    }
    if (cc < 56) {
#pragma unroll
      for (int j = 0; j < 8; ++j) xv[j] = xn[j];
    }
  }
}

// ---------------------------------------------------------------------------
// Workspace layout (float units):
//   f16  @ 0        (884736 fl = [b][n][32] bf16)
//   g16  @ 884736   (884736 fl = [b][c][n] bf16)
//   h16  @ 1769472  (884736)
//   gt16 @ 4423680  (110592 fl = [b][m][c] bf16)
//   ht16 @ 4534272  (110592 fl = [b][c][m] bf16)
//   W16c @ 4644864  (12288 fl = 24576 bf16)
// (o region @2654208 now unused — out-projection fused into attn.)
// ---------------------------------------------------------------------------
extern "C" void kernel_launch(void* const* d_in, const int* in_sizes, int n_in,
                              void* d_out, int out_size, void* d_ws, size_t ws_size,
                              hipStream_t stream) {
  const float* x     = (const float*)d_in[0];
  const float* Wf    = (const float*)d_in[1];
  const float* Wg    = (const float*)d_in[2];
  const float* Wh    = (const float*)d_in[3];
  const float* Wv    = (const float*)d_in[4];
  const float* gamma = (const float*)d_in[5];
  float* out = (float*)d_out;
  float* ws = (float*)d_ws;

  unsigned short* f16  = (unsigned short*)ws;
  unsigned short* g16  = (unsigned short*)(ws + 884736);
  unsigned short* h16  = (unsigned short*)(ws + 1769472);
  unsigned short* gt16 = (unsigned short*)(ws + 4423680);
  unsigned short* ht16 = (unsigned short*)(ws + 4534272);
  unsigned short* W16c = (unsigned short*)(ws + 4644864);

  wcvt_kernel<<<96, 256, 0, stream>>>(Wf, Wg, Wh, W16c);
  proj_mfma<<<B * 108, 256, 0, stream>>>(x, W16c, f16, g16, h16);
  pool_kernel<<<(B * CQ * MM) / 256, 256, 0, stream>>>(g16, h16, gt16, ht16);
  attn_kernel<<<B * (NN / 64), 256, 0, stream>>>(f16, gt16, ht16, x, Wv, gamma, out);
}

// Round 2
// 167.790 us; speedup vs baseline: 1.1973x; 1.1149x over previous
//
#include <hip/hip_runtime.h>

#define B 4
#define C 256
#define CQ 32
#define NN 13824   // 24^3
#define MM 1728    // 12^3
#define MS 12

typedef __attribute__((ext_vector_type(8))) short short8;    // 8 bf16 = 4 VGPRs
typedef __attribute__((ext_vector_type(4))) float float4_;   // 16x16 MFMA C/D
typedef __attribute__((ext_vector_type(16))) float floatx16; // 32x32 MFMA C/D

static __device__ inline unsigned rne_bf16(float x) {
  unsigned u = __float_as_uint(x);
  u += 0x7FFFu + ((u >> 16) & 1u);   // round-to-nearest-even bf16
  return u >> 16;
}

// ---------------------------------------------------------------------------
// K0: pack Wf/Wg/Wh -> bf16 W16c (A-fragment order for proj_mfma), and
//     Wv (fp32 [256][32]) -> double-bf16 pair Whv/Wlv (hi + residual-lo),
//     row-major [c][q], used by attn's MFMA out-projection.
// ---------------------------------------------------------------------------
__global__ __launch_bounds__(256) void wcvt_kernel(
    const float* __restrict__ Wf, const float* __restrict__ Wg,
    const float* __restrict__ Wh, const float* __restrict__ Wv,
    unsigned short* __restrict__ W16c, unsigned short* __restrict__ Whv,
    unsigned short* __restrict__ Wlv) {
  const int i = blockIdx.x * 256 + threadIdx.x;   // [0, 32768)
  if (i < 24576) {
    const int kk = i & 7;
    const int rest = i >> 3;
    const int m = rest % 96;
    const int r = rest / 96;
    const int kq = r & 3;
    const int ch = r >> 2;
    const int k = ch * 32 + kq * 8 + kk;
    const float* Wr = (m < 32) ? (Wf + m * C) : (m < 64) ? (Wg + (m - 32) * C)
                                                         : (Wh + (m - 64) * C);
    W16c[i] = (unsigned short)rne_bf16(Wr[k]);
  } else {
    const int j = i - 24576;            // [0, 8192) = c*32 + q for Wv[256][32]
    const float v = Wv[j];
    const unsigned h = rne_bf16(v);
    Whv[j] = (unsigned short)h;
    Wlv[j] = (unsigned short)rne_bf16(v - __uint_as_float(h << 16));
  }
}

// ---------------------------------------------------------------------------
// K1: projections as MFMA GEMM.  [96,256] x [256, NN] per batch.
// r7: 2-chunk-deep register prefetch (T14 issue-early/write-late) + full
// unroll so all LDS buffer indices are static and the compiler can emit
// counted vmcnt (the old rolled loop stalled ~800 cyc per chunk waiting on
// staging loads at 1.7 waves/SIMD occupancy).
// ---------------------------------------------------------------------------
#define LOADX(SET, CH)                                                        \
  do {                                                                        \
    const float* xp = xbase + (size_t)((CH)*32) * NN;                         \
    _Pragma("unroll") for (int it = 0; it < 2; ++it) {                        \
      _Pragma("unroll") for (int kk = 0; kk < 8; ++kk)                        \
          vx[SET][it][kk] = xp[(size_t)((sh * 2 + it) * 8 + kk) * NN];        \
    }                                                                         \
  } while (0)

#define PACKX(SET, BUF)                                                       \
  do {                                                                        \
    _Pragma("unroll") for (int it = 0; it < 2; ++it) {                        \
      const int kq = sh * 2 + it;                                             \
      *reinterpret_cast<uint4*>(&xls[BUF][kq][sn][0]) = make_uint4(           \
          rne_bf16(vx[SET][it][0]) | (rne_bf16(vx[SET][it][1]) << 16),        \
          rne_bf16(vx[SET][it][2]) | (rne_bf16(vx[SET][it][3]) << 16),        \
          rne_bf16(vx[SET][it][4]) | (rne_bf16(vx[SET][it][5]) << 16),        \
          rne_bf16(vx[SET][it][6]) | (rne_bf16(vx[SET][it][7]) << 16));       \
    }                                                                         \
  } while (0)

#define LOADW(CH)                                                             \
  do {                                                                        \
    const uint4* src = reinterpret_cast<const uint4*>(W16c + (size_t)(CH)*3072); \
    wr0 = src[t];                                                             \
    if (t < 128) wr1 = src[256 + t];                                          \
  } while (0)

#define STOREW(BUF)                                                           \
  do {                                                                        \
    uint4* dst = reinterpret_cast<uint4*>(&wls[BUF][0][0][0]);                \
    dst[t] = wr0;                                                             \
    if (t < 128) dst[256 + t] = wr1;                                          \
  } while (0)

#define COMPUTE(BUF)                                                          \
  do {                                                                        \
    _Pragma("unroll") for (int ks = 0; ks < 2; ++ks) {                        \
      const int kq = ks * 2 + hi;                                             \
      const short8 bfr =                                                      \
          *reinterpret_cast<const short8*>(&xls[BUF][kq][w * 32 + col][0]);   \
      const short8 a0 = *reinterpret_cast<const short8*>(&wls[BUF][kq][col][0]);      \
      const short8 a1 = *reinterpret_cast<const short8*>(&wls[BUF][kq][32 + col][0]); \
      const short8 a2 = *reinterpret_cast<const short8*>(&wls[BUF][kq][64 + col][0]); \
      accf = __builtin_amdgcn_mfma_f32_32x32x16_bf16(a0, bfr, accf, 0, 0, 0); \
      accg = __builtin_amdgcn_mfma_f32_32x32x16_bf16(a1, bfr, accg, 0, 0, 0); \
      acch = __builtin_amdgcn_mfma_f32_32x32x16_bf16(a2, bfr, acch, 0, 0, 0); \
    }                                                                         \
  } while (0)

__global__ __launch_bounds__(256) void proj_mfma(
    const float* __restrict__ x, const unsigned short* __restrict__ W16c,
    unsigned short* __restrict__ f16, unsigned short* __restrict__ g16,
    unsigned short* __restrict__ h16) {
  __shared__ __align__(16) unsigned short xls[2][4][128][8];  // 16 KB
  __shared__ __align__(16) unsigned short wls[2][4][96][8];   // 12 KB
  const int blk = blockIdx.x;
  const int b = blk / 108;
  const int n0 = (blk - b * 108) * 128;
  const int t = threadIdx.x;
  const int w = t >> 6, lane = t & 63;
  const int col = lane & 31, hi = lane >> 5;
  const int sn = t & 127, sh = t >> 7;            // staging: n, k-half

  floatx16 accf = {0}, accg = {0}, acch = {0};
  const float* xbase = x + ((size_t)b * C) * NN + n0 + sn;
  float vx[2][2][8];        // two in-flight register chunk sets (static idx)
  uint4 wr0, wr1;

  // prologue: chunk0 -> LDS[0]; chunk1 -> regs (set1)
  LOADX(0, 0);
  PACKX(0, 0);
  LOADW(0);
  STOREW(0);
  LOADX(1, 1);
  __syncthreads();

#pragma unroll
  for (int ch = 0; ch < 8; ++ch) {
    const int buf = ch & 1;
    if (ch + 1 < 8) LOADW(ch + 1);                // W next chunk -> regs
    if (ch + 2 < 8) {                             // x chunk+2 -> freed reg set
      if (buf == 0) LOADX(0, ch + 2); else LOADX(1, ch + 2);
    }
    COMPUTE(buf);
    if (ch + 1 < 8) {                             // write-late: ch+1 -> LDS
      if (buf == 0) PACKX(1, 1); else PACKX(0, 0);
      STOREW(buf ^ 1);
      __syncthreads();
    }
  }

  // ---- epilogue. D layout: col=lane&31 (x n-index), row=(r&3)+8*(r>>2)+4*hi.
  const int n = n0 + w * 32 + col;
  {  // f: bf16 [b][n][c], pack row-pairs -> 8 dword stores
    unsigned short* fp = f16 + ((size_t)b * NN + n) * 32 + hi * 4;
#pragma unroll
    for (int rp = 0; rp < 8; ++rp) {
      const int m = (rp & 1) * 2 + 8 * (rp >> 1);   // 0,2,8,10,16,18,24,26
      *reinterpret_cast<unsigned*>(fp + m) =
          rne_bf16(accf[rp * 2]) | (rne_bf16(accf[rp * 2 + 1]) << 16);
    }
  }
  unsigned short* gp = g16 + (size_t)b * CQ * NN + n;
  unsigned short* hp = h16 + (size_t)b * CQ * NN + n;
#pragma unroll
  for (int r = 0; r < 16; ++r) {
    const int c = (r & 3) + 8 * (r >> 2) + 4 * hi;
    gp[(size_t)c * NN] = (unsigned short)rne_bf16(accg[r]);
    hp[(size_t)c * NN] = (unsigned short)rne_bf16(acch[r]);
  }
}

// ---------------------------------------------------------------------------
// K2: 2x2x2 maxpool, bf16 in -> bf16 out. (unchanged)
// ---------------------------------------------------------------------------
__global__ __launch_bounds__(256) void pool_kernel(
    const unsigned short* __restrict__ g16, const unsigned short* __restrict__ h16,
    unsigned short* __restrict__ gt16, unsigned short* __restrict__ ht16) {
  int i = blockIdx.x * 256 + threadIdx.x;            // [0, B*CQ*MM)
  const int c = i & 31;
  const int rest = i >> 5;
  const int m = rest % MM;
  const int b = rest / MM;
  const int wq = m % MS;
  const int hq = (m / MS) % MS;
  const int dq = m / (MS * MS);
  const size_t base = ((size_t)b * CQ + c) * NN +
                      (2 * dq) * 576 + (2 * hq) * 24 + (2 * wq);
  auto mx2 = [](unsigned u) {
    return fmaxf(__uint_as_float(u << 16), __uint_as_float(u & 0xFFFF0000u));
  };
  const unsigned short* pg = g16 + base;
  const unsigned short* ph = h16 + base;
  float vg = fmaxf(fmaxf(mx2(*(const unsigned*)(pg)),
                         mx2(*(const unsigned*)(pg + 24))),
                   fmaxf(mx2(*(const unsigned*)(pg + 576)),
                         mx2(*(const unsigned*)(pg + 600))));
  float vh = fmaxf(fmaxf(mx2(*(const unsigned*)(ph)),
                         mx2(*(const unsigned*)(ph + 24))),
                   fmaxf(mx2(*(const unsigned*)(ph + 576)),
                         mx2(*(const unsigned*)(ph + 600))));
  gt16[((size_t)b * MM + m) * 32 + c] = (unsigned short)(__float_as_uint(vg) >> 16);
  ht16[((size_t)b * 32 + c) * MM + m] = (unsigned short)(__float_as_uint(vh) >> 16);
}

// ---------------------------------------------------------------------------
// K3: MFMA flash attention + MFMA out-projection/residual.
// Main loop unchanged. Epilogue r7: instead of a 2048-FMA VALU dot per
// thread (=4096 cyc/wave, the kernel's largest VALU block), the 256x64x32
// out-GEMM per block now runs on the matrix pipe: o -> ols[64][33] fp32
// (conflict-free), each lane builds bf16 B-frags from 8 contiguous floats,
// A = double-bf16 Wv (hi+lo, fp32-accurate), 16x 32x32x16 MFMA per wave.
// ---------------------------------------------------------------------------
__global__ __launch_bounds__(256, 4) void attn_kernel(
    const unsigned short* __restrict__ f16, const unsigned short* __restrict__ gt,
    const unsigned short* __restrict__ ht, const float* __restrict__ x,
    const unsigned short* __restrict__ Whv, const unsigned short* __restrict__ Wlv,
    const float* __restrict__ gamma, float* __restrict__ out) {
  __shared__ __align__(16) unsigned short sm[16896];
  const int blk = blockIdx.x;               // 864
  const int b = blk / 216;
  const int n0 = (blk - b * 216) * 64;
  const int t = threadIdx.x;
  const int w = t >> 6, L = t & 63, Q = L >> 4, col = L & 15;

  unsigned short* fls = sm;
  unsigned short* g0 = sm + 2560;
  unsigned short* g1 = sm + 5120;
  unsigned short* h0 = sm + 7680;
  unsigned short* h1 = sm + 9984;
  unsigned short* Pls = sm + 12288 + w * 1152;

  {
    const unsigned short* fsrc = f16 + ((size_t)(b * NN + n0)) * 32;
    *reinterpret_cast<uint4*>(fls + (t >> 2) * 40 + (t & 3) * 8) =
        *reinterpret_cast<const uint4*>(fsrc + t * 8);
  }
  const unsigned short* gsrc = gt + (size_t)b * MM * 32;
  const unsigned short* hsrc = ht + (size_t)b * 32 * MM;
  const int gk = t >> 2, gseg = t & 3;
  const int hc = t >> 3, hseg = t & 7;
  *reinterpret_cast<uint4*>(g0 + gk * 40 + gseg * 8) =
      *reinterpret_cast<const uint4*>(gsrc + gk * 32 + gseg * 8);
  *reinterpret_cast<uint4*>(h0 + hc * 72 + hseg * 8) =
      *reinterpret_cast<const uint4*>(hsrc + (size_t)hc * MM + hseg * 8);
  __syncthreads();

  const short8 fB = *reinterpret_cast<const short8*>(fls + (w * 16 + col) * 40 + Q * 8);

  float4_ acc0 = {0.f, 0.f, 0.f, 0.f}, acc1 = {0.f, 0.f, 0.f, 0.f};
  float l = 0.f;

  for (int ch = 0; ch < 27; ++ch) {
    unsigned short* gcur = (ch & 1) ? g1 : g0;
    unsigned short* hcur = (ch & 1) ? h1 : h0;
    uint4 gnx, hnx;
    if (ch < 26) {
      const int k0 = (ch + 1) * 64;
      gnx = *reinterpret_cast<const uint4*>(gsrc + (size_t)(k0 + gk) * 32 + gseg * 8);
      hnx = *reinterpret_cast<const uint4*>(hsrc + (size_t)hc * MM + k0 + hseg * 8);
    }
    float4_ sc[4];
#pragma unroll
    for (int T = 0; T < 4; ++T) {
      const short8 gA =
          *reinterpret_cast<const short8*>(gcur + (T * 16 + col) * 40 + Q * 8);
      float4_ z = {0.f, 0.f, 0.f, 0.f};
      sc[T] = __builtin_amdgcn_mfma_f32_16x16x32_bf16(gA, fB, z, 0, 0, 0);
    }
#pragma unroll
    for (int T = 0; T < 4; ++T) {
      const float p0 = __expf(sc[T][0] - 30.f);
      const float p1 = __expf(sc[T][1] - 30.f);
      const float p2 = __expf(sc[T][2] - 30.f);
      const float p3 = __expf(sc[T][3] - 30.f);
      l += (p0 + p1) + (p2 + p3);
      unsigned short* pw = Pls + col * 72 + T * 16 + Q * 4;
      *reinterpret_cast<uint2*>(pw) =
          make_uint2(rne_bf16(p0) | (rne_bf16(p1) << 16),
                     rne_bf16(p2) | (rne_bf16(p3) << 16));
    }
#pragma unroll
    for (int ks = 0; ks < 2; ++ks) {
      const short8 pA =
          *reinterpret_cast<const short8*>(Pls + col * 72 + ks * 32 + Q * 8);
      const short8 hB0 =
          *reinterpret_cast<const short8*>(hcur + col * 72 + ks * 32 + Q * 8);
      const short8 hB1 =
          *reinterpret_cast<const short8*>(hcur + (16 + col) * 72 + ks * 32 + Q * 8);
      acc0 = __builtin_amdgcn_mfma_f32_16x16x32_bf16(pA, hB0, acc0, 0, 0, 0);
      acc1 = __builtin_amdgcn_mfma_f32_16x16x32_bf16(pA, hB1, acc1, 0, 0, 0);
    }
    if (ch < 26) {
      unsigned short* gnb = (ch & 1) ? g0 : g1;
      unsigned short* hnb = (ch & 1) ? h0 : h1;
      *reinterpret_cast<uint4*>(gnb + gk * 40 + gseg * 8) = gnx;
      *reinterpret_cast<uint4*>(hnb + hc * 72 + hseg * 8) = hnx;
    }
    __syncthreads();
  }

  // ---- softmax denominator + park o in LDS (stride 33: conflict-free).
  l += __shfl_xor(l, 16);
  l += __shfl_xor(l, 32);
  float* ols = reinterpret_cast<float*>(sm);   // [64][33] fp32 = 8448 B
#pragma unroll
  for (int r = 0; r < 4; ++r) {
    const float linv = 1.f / __shfl(l, Q * 4 + r);
    const int nl = w * 16 + Q * 4 + r;
    ols[nl * 33 + col] = acc0[r] * linv;
    ols[nl * 33 + 16 + col] = acc1[r] * linv;
  }
  __syncthreads();

  // ---- MFMA out-projection: D[256 c][64 n] = (Whv+Wlv) @ o^T, + gamma/x.
  // B-frag (o): lane reads ols[(nt*32+colA)][ks*16+hiA*8 + 0..7] (contiguous,
  // stride-33 -> conflict-free), packs to bf16. A-frag (Wv): 16B/lane global.
  const int colA = L & 31, hiA = L >> 5;
  const float gm = gamma[0];
  short8 Bf[2][2];
#pragma unroll
  for (int nt = 0; nt < 2; ++nt) {
#pragma unroll
    for (int ks = 0; ks < 2; ++ks) {
      const float* p = &ols[(nt * 32 + colA) * 33 + ks * 16 + hiA * 8];
      uint4 uu;
      uu.x = rne_bf16(p[0]) | (rne_bf16(p[1]) << 16);
      uu.y = rne_bf16(p[2]) | (rne_bf16(p[3]) << 16);
      uu.z = rne_bf16(p[4]) | (rne_bf16(p[5]) << 16);
      uu.w = rne_bf16(p[6]) | (rne_bf16(p[7]) << 16);
      Bf[nt][ks] = *reinterpret_cast<short8*>(&uu);
    }
  }
#pragma unroll
  for (int tt = 0; tt < 2; ++tt) {
    const int ct = w + tt * 4;                   // c-tile 0..7
    const int ca = ct * 32 + colA;               // A row = out channel
    const short8 Ah0 = *reinterpret_cast<const short8*>(Whv + ca * 32 + hiA * 8);
    const short8 Ah1 = *reinterpret_cast<const short8*>(Whv + ca * 32 + 16 + hiA * 8);
    const short8 Al0 = *reinterpret_cast<const short8*>(Wlv + ca * 32 + hiA * 8);
    const short8 Al1 = *reinterpret_cast<const short8*>(Wlv + ca * 32 + 16 + hiA * 8);
    floatx16 ac0 = {0}, ac1 = {0};
    ac0 = __builtin_amdgcn_mfma_f32_32x32x16_bf16(Ah0, Bf[0][0], ac0, 0, 0, 0);
    ac0 = __builtin_amdgcn_mfma_f32_32x32x16_bf16(Ah1, Bf[0][1], ac0, 0, 0, 0);
    ac0 = __builtin_amdgcn_mfma_f32_32x32x16_bf16(Al0, Bf[0][0], ac0, 0, 0, 0);
    ac0 = __builtin_amdgcn_mfma_f32_32x32x16_bf16(Al1, Bf[0][1], ac0, 0, 0, 0);
    ac1 = __builtin_amdgcn_mfma_f32_32x32x16_bf16(Ah0, Bf[1][0], ac1, 0, 0, 0);
    ac1 = __builtin_amdgcn_mfma_f32_32x32x16_bf16(Ah1, Bf[1][1], ac1, 0, 0, 0);
    ac1 = __builtin_amdgcn_mfma_f32_32x32x16_bf16(Al0, Bf[1][0], ac1, 0, 0, 0);
    ac1 = __builtin_amdgcn_mfma_f32_32x32x16_bf16(Al1, Bf[1][1], ac1, 0, 0, 0);
#pragma unroll
    for (int nt = 0; nt < 2; ++nt) {
      const floatx16 av = nt ? ac1 : ac0;
      const int n = n0 + nt * 32 + colA;
      const float* xp = x + ((size_t)b * C + ct * 32 + 4 * hiA) * NN + n;
      float* op = out + ((size_t)b * C + ct * 32 + 4 * hiA) * NN + n;
      float xv[16];
#pragma unroll
      for (int r = 0; r < 16; ++r)
        xv[r] = xp[(size_t)((r & 3) + 8 * (r >> 2)) * NN];
#pragma unroll
      for (int r = 0; r < 16; ++r)
        op[(size_t)((r & 3) + 8 * (r >> 2)) * NN] = gm * av[r] + xv[r];
    }
  }
}

// ---------------------------------------------------------------------------
// Workspace layout (float units):
//   f16  @ 0        (884736 fl = [b][n][32] bf16)
//   g16  @ 884736   (884736 fl = [b][c][n] bf16)
//   h16  @ 1769472  (884736)
//   Whv  @ 2654208  (4096 fl = 8192 bf16)   <- reuses dead o region
//   Wlv  @ 2658304  (4096 fl = 8192 bf16)
//   gt16 @ 4423680  (110592 fl = [b][m][c] bf16)
//   ht16 @ 4534272  (110592 fl = [b][c][m] bf16)
//   W16c @ 4644864  (12288 fl = 24576 bf16)
// ---------------------------------------------------------------------------
extern "C" void kernel_launch(void* const* d_in, const int* in_sizes, int n_in,
                              void* d_out, int out_size, void* d_ws, size_t ws_size,
                              hipStream_t stream) {
  const float* x     = (const float*)d_in[0];
  const float* Wf    = (const float*)d_in[1];
  const float* Wg    = (const float*)d_in[2];
  const float* Wh    = (const float*)d_in[3];
  const float* Wv    = (const float*)d_in[4];
  const float* gamma = (const float*)d_in[5];
  float* out = (float*)d_out;
  float* ws = (float*)d_ws;

  unsigned short* f16  = (unsigned short*)ws;
  unsigned short* g16  = (unsigned short*)(ws + 884736);
  unsigned short* h16  = (unsigned short*)(ws + 1769472);
  unsigned short* Whv  = (unsigned short*)(ws + 2654208);
  unsigned short* Wlv  = (unsigned short*)(ws + 2658304);
  unsigned short* gt16 = (unsigned short*)(ws + 4423680);
  unsigned short* ht16 = (unsigned short*)(ws + 4534272);
  unsigned short* W16c = (unsigned short*)(ws + 4644864);

  wcvt_kernel<<<128, 256, 0, stream>>>(Wf, Wg, Wh, Wv, W16c, Whv, Wlv);
  proj_mfma<<<B * 108, 256, 0, stream>>>(x, W16c, f16, g16, h16);
  pool_kernel<<<(B * CQ * MM) / 256, 256, 0, stream>>>(g16, h16, gt16, ht16);
  attn_kernel<<<B * (NN / 64), 256, 0, stream>>>(f16, gt16, ht16, x, Whv, Wlv,
                                                 gamma, out);
}